// Round 3
// baseline (8162.756 us; speedup 1.0000x reference)
//
#include <hip/hip_runtime.h>
#include <hip/hip_fp16.h>
#include <stdint.h>

#define Kn 64
#define En 256
#define Bn 512
#define Hn 512
#define Dn 128
#define NB 256       // blocks (2 samples each)
#define NT 1024      // 16 waves
#define DT_C 0.05f

// ws layout (bytes):
//   [0, 131072)      pos (int, Kn*Bn): pos[k*Bn+b] = e or -1
//   [131072, 131080) acc (float x2): loss, tot_m
//   [131584, ...)    f16 weights (__half), 16B-aligned
// half-unit offsets: W1 0, W2 262144, Wp1 524288, Wp2 786432, Wg 851968
//   Wg is the 4 gate matrices interleaved: [640 rows][2048 = g*512+j]

__device__ __forceinline__ float sigm(float x){ return 1.0f/(1.0f + __expf(-x)); }

__global__ void k_init(int* __restrict__ pos, float* __restrict__ acc){
  int i = blockIdx.x*blockDim.x + threadIdx.x;
  if (i < Kn*Bn) pos[i] = -1;
  if (i < 2) acc[i] = 0.0f;
}

__global__ void k_scatter(const int* __restrict__ bidx, int* __restrict__ pos){
  int i = blockIdx.x*blockDim.x + threadIdx.x;
  if (i < Kn*En){
    int k = i >> 8;
    int e = i & (En-1);
    pos[(k << 9) | bidx[i]] = e;
  }
}

__global__ void k_cvt(const float* __restrict__ src, __half* __restrict__ dst, int n){
  int i = blockIdx.x*blockDim.x + threadIdx.x;
  if (i < n) dst[i] = __float2half(src[i]);
}

__global__ void k_cvt_g(const float* __restrict__ src, __half* __restrict__ dst, int g){
  int i = blockIdx.x*blockDim.x + threadIdx.x;
  if (i < 640*512){
    int r = i >> 9, j = i & 511;
    dst[(size_t)r*2048 + g*512 + j] = __float2half(src[i]);
  }
}

// 8 fp32 FMAs from one uint4 (8 f16 weights); compiler emits v_fma_mix_f32
#define FMA8(HV, U) do{                                                \
  const __half2* _hp = reinterpret_cast<const __half2*>(&(U));         \
  a[0]=fmaf((HV), __low2float (_hp[0]), a[0]);                         \
  a[1]=fmaf((HV), __high2float(_hp[0]), a[1]);                         \
  a[2]=fmaf((HV), __low2float (_hp[1]), a[2]);                         \
  a[3]=fmaf((HV), __high2float(_hp[1]), a[3]);                         \
  a[4]=fmaf((HV), __low2float (_hp[2]), a[4]);                         \
  a[5]=fmaf((HV), __high2float(_hp[2]), a[5]);                         \
  a[6]=fmaf((HV), __low2float (_hp[3]), a[6]);                         \
  a[7]=fmaf((HV), __high2float(_hp[3]), a[7]);                         \
}while(0)

// 512x512 matvec partial: rows [kcE*64,+64), cols [cgE*8,+8), sample s
__device__ __forceinline__ void dot512(const float* __restrict__ vin,
                                       const __half* __restrict__ W,
                                       float* __restrict__ part,
                                       int cgE, int kcE, int s)
{
  float a[8];
  #pragma unroll
  for (int i=0;i<8;i++) a[i]=0.f;
  const int r0 = kcE*64;
  #pragma unroll 8
  for (int i=0;i<64;i++){
    const int r = r0 + i;
    const float hv = vin[r];
    uint4 u = *reinterpret_cast<const uint4*>(W + (size_t)r*512 + cgE*8);
    FMA8(hv, u);
  }
  float* pb = part + kcE*1024 + s*512 + cgE*8;
  *(float4*)(pb)   = make_float4(a[0],a[1],a[2],a[3]);
  *(float4*)(pb+4) = make_float4(a[4],a[5],a[6],a[7]);
}

// gates: [x(128);h(512)] @ Wg(640x2048); cols [cgG*8,+8), K split in 2 halves of 320
__device__ __forceinline__ void dot640(const float* __restrict__ shx,
                                       const float* __restrict__ shh,
                                       const __half* __restrict__ W,
                                       float* __restrict__ part2,
                                       int cgG, int kcG, int s)
{
  float a[8];
  #pragma unroll
  for (int i=0;i<8;i++) a[i]=0.f;
  if (kcG == 0){
    #pragma unroll 8
    for (int r=0;r<128;r++){
      const float hv = shx[s*128 + r];
      uint4 u = *reinterpret_cast<const uint4*>(W + (size_t)r*2048 + cgG*8);
      FMA8(hv, u);
    }
    #pragma unroll 8
    for (int r=0;r<192;r++){
      const float hv = shh[s*512 + r];
      uint4 u = *reinterpret_cast<const uint4*>(W + (size_t)(128+r)*2048 + cgG*8);
      FMA8(hv, u);
    }
  } else {
    #pragma unroll 8
    for (int r=192;r<512;r++){
      const float hv = shh[s*512 + r];
      uint4 u = *reinterpret_cast<const uint4*>(W + (size_t)(128+r)*2048 + cgG*8);
      FMA8(hv, u);
    }
  }
  float* pb = part2 + kcG*4096 + s*2048 + cgG*8;
  *(float4*)(pb)   = make_float4(a[0],a[1],a[2],a[3]);
  *(float4*)(pb+4) = make_float4(a[4],a[5],a[6],a[7]);
}

// Wp2 (512x128): rows [kc2*16,+16), cols [cg4*8,+8)
__device__ __forceinline__ void dotp2(const float* __restrict__ vin,
                                      const __half* __restrict__ W,
                                      float* __restrict__ part,
                                      int cg4, int kc2, int s)
{
  float a[8];
  #pragma unroll
  for (int i=0;i<8;i++) a[i]=0.f;
  const int r0 = kc2*16;
  #pragma unroll
  for (int i=0;i<16;i++){
    const int r = r0 + i;
    const float hv = vin[r];
    uint4 u = *reinterpret_cast<const uint4*>(W + (size_t)r*128 + cg4*8);
    FMA8(hv, u);
  }
  float* pb = part + kc2*256 + s*128 + cg4*8;
  *(float4*)(pb)   = make_float4(a[0],a[1],a[2],a[3]);
  *(float4*)(pb+4) = make_float4(a[4],a[5],a[6],a[7]);
}

__device__ __forceinline__ float red8(const float* __restrict__ part, int t){
  float r = part[t];
  #pragma unroll
  for (int q=1;q<8;q++) r += part[q*1024 + t];
  return r;
}

__global__ __launch_bounds__(NT) void k_main(
  const float* __restrict__ X, const float* __restrict__ Mm,
  const int* __restrict__ pos, const __half* __restrict__ Wh,
  const float* __restrict__ bi_, const float* __restrict__ bf_,
  const float* __restrict__ bo_, const float* __restrict__ bc_,
  const float* __restrict__ b1_, const float* __restrict__ b2_,
  const float* __restrict__ bp1_, const float* __restrict__ bp2_,
  float* __restrict__ acc)
{
  const __half* W1h  = Wh;
  const __half* W2h  = Wh + 262144;
  const __half* Wp1h = Wh + 524288;
  const __half* Wp2h = Wh + 786432;
  const __half* Wgh  = Wh + 851968;

  const int t   = threadIdx.x;
  const int b   = blockIdx.x;
  const int s   = t >> 9;           // sample within pair
  const int j   = t & 511;          // hidden index
  const int cgE = t & 63;           // 8-col group (Euler/p1)
  const int kcE = (t >> 6) & 7;     // K chunk of 64
  const int cgG = t & 255;          // 8-col group (gates, 2048 cols)
  const int kcG = (t >> 8) & 1;     // K half of 320
  const int cg4 = t & 15;           // 8-col group (p2, 128 cols)
  const int kc2 = (t >> 4) & 31;    // K chunk of 16

  __shared__ float sh_h[2*Hn];      // [s][j]
  __shared__ float sh_c[2*Hn];
  __shared__ float sh_t[2*Hn];
  __shared__ float sh_x[2*Dn];      // [s][d]
  __shared__ float part [8*1024];   // 32KB
  __shared__ float part2[2*4096];   // 32KB (gates)
  __shared__ float red[32];

  sh_h[t] = 0.f;
  sh_c[t] = 0.f;

  const float vb1 = b1_[j], vb2 = b2_[j], vbp1 = bp1_[j];
  const float vgi = bi_[j], vgf = bf_[j], vgo = bo_[j], vgc = bc_[j];
  float vbp2 = 0.f;
  if (t < 2*Dn) vbp2 = bp2_[t & (Dn-1)];

  float loss_loc = 0.f, m_loc = 0.f;

  for (int k=0;k<Kn;k++){
    const int e0 = pos[(k<<9) + 2*b];
    const int e1 = pos[(k<<9) + 2*b + 1];
    const bool obs = (e0 >= 0) || (e1 >= 0);
    if (k == Kn-1 && !obs) break;          // block-uniform; nothing left matters

    // ---- 2 Euler steps (both samples) ----
    for (int st=0; st<2; st++){
      __syncthreads();                     // h stable, part free
      dot512(sh_h + s*512, W1h, part, cgE, kcE, s);
      __syncthreads();                     // partials done
      sh_t[t] = tanhf(red8(part, t) + vb1);
      __syncthreads();                     // t visible, part reads done
      dot512(sh_t + s*512, W2h, part, cgE, kcE, s);
      __syncthreads();
      sh_h[t] += DT_C * (red8(part, t) + vb2);
    }

    if (!obs) continue;                    // next event (lead bar covers h)

    // stage X rows (zeros for unobserved sample)
    if (t < 2*Dn){
      const int es2 = (t >> 7) ? e1 : e0;
      float v = 0.f;
      if (es2 >= 0) v = X[((size_t)(k*En+es2))*Dn + (t & (Dn-1))];
      sh_x[t] = v;
    }
    __syncthreads();                       // x staged, h final, part free

    // p_model layer 1
    dot512(sh_h + s*512, Wp1h, part, cgE, kcE, s);
    __syncthreads();
    sh_t[t] = fmaxf(red8(part, t) + vbp1, 0.f);
    __syncthreads();
    // p_model layer 2
    dotp2(sh_t + s*512, Wp2h, part, cg4, kc2, s);
    __syncthreads();
    // loss tail (t<256) overlaps gate dot (disjoint buffers)
    if (t < 2*Dn){
      const int es2 = (t >> 7) ? e1 : e0;
      if (es2 >= 0){
        float p = vbp2;
        #pragma unroll
        for (int q=0;q<32;q++) p += part[q*256 + t];
        float m  = Mm[((size_t)(k*En+es2))*Dn + (t & (Dn-1))];
        float xo = sh_x[t];
        loss_loc += fabsf(xo - p) * m;
        m_loc    += m;
      }
    }

    // LSTM gates (dead at last event)
    if (k < Kn-1){
      dot640(sh_x, sh_h, Wgh, part2, cgG, kcG, s);
      __syncthreads();                     // gate partials done (h reads done too)
      const int es = s ? e1 : e0;
      if (es >= 0){
        const float* pz = part2 + s*2048;
        float pi = pz[j]        + pz[4096 + j];
        float pf = pz[512 + j]  + pz[4096 + 512 + j];
        float po = pz[1024 + j] + pz[4096 + 1024 + j];
        float pc = pz[1536 + j] + pz[4096 + 1536 + j];
        float ig = sigm(pi + vgi), fg = sigm(pf + vgf);
        float og = sigm(po + vgo), ct = tanhf(pc + vgc);
        float cn = fg*sh_c[t] + ig*ct;
        sh_c[t] = cn;
        sh_h[t] = og * tanhf(cn);
      }
    }
  }

  // block reduction -> global atomics
  #pragma unroll
  for (int off=32; off>0; off>>=1){
    loss_loc += __shfl_down(loss_loc, off);
    m_loc    += __shfl_down(m_loc, off);
  }
  const int wid = t >> 6, lane = t & 63;
  if (lane == 0){ red[wid] = loss_loc; red[16+wid] = m_loc; }
  __syncthreads();
  if (t == 0){
    float L = 0.f, Mt = 0.f;
    #pragma unroll
    for (int w2=0; w2<16; w2++){ L += red[w2]; Mt += red[16+w2]; }
    atomicAdd(acc+0, L);
    atomicAdd(acc+1, Mt);
  }
}

__global__ void k_fin(const float* __restrict__ acc, float* __restrict__ out){
  if (threadIdx.x == 0){
    out[0] = acc[0];
    out[1] = acc[0]/acc[1];
  }
}

extern "C" void kernel_launch(void* const* d_in, const int* in_sizes, int n_in,
                              void* d_out, int out_size, void* d_ws, size_t ws_size,
                              hipStream_t stream)
{
  const float* X   = (const float*)d_in[0];
  const float* Mm  = (const float*)d_in[1];
  const int*  bidx = (const int*)d_in[2];
  // d_in[3] = sample_idx (unused, arange)
  const float* Wi  = (const float*)d_in[4];
  const float* bi  = (const float*)d_in[5];
  const float* Wf  = (const float*)d_in[6];
  const float* bff = (const float*)d_in[7];
  const float* Wo  = (const float*)d_in[8];
  const float* bo  = (const float*)d_in[9];
  const float* Wc  = (const float*)d_in[10];
  const float* bc  = (const float*)d_in[11];
  const float* W1  = (const float*)d_in[12];
  const float* b1  = (const float*)d_in[13];
  const float* W2  = (const float*)d_in[14];
  const float* b2  = (const float*)d_in[15];
  const float* Wp1 = (const float*)d_in[16];
  const float* bp1 = (const float*)d_in[17];
  const float* Wp2 = (const float*)d_in[18];
  const float* bp2 = (const float*)d_in[19];

  char* ws = (char*)d_ws;
  int*    pos = (int*)ws;
  float*  acc = (float*)(ws + 131072);
  __half* wh  = (__half*)(ws + 131584);

  k_init   <<<(Kn*Bn + 255)/256, 256, 0, stream>>>(pos, acc);
  k_scatter<<<(Kn*En + 255)/256, 256, 0, stream>>>(bidx, pos);

  k_cvt<<<(Hn*Hn + 255)/256, 256, 0, stream>>>(W1,  wh + 0,      Hn*Hn);
  k_cvt<<<(Hn*Hn + 255)/256, 256, 0, stream>>>(W2,  wh + 262144, Hn*Hn);
  k_cvt<<<(Hn*Hn + 255)/256, 256, 0, stream>>>(Wp1, wh + 524288, Hn*Hn);
  k_cvt<<<(Hn*Dn + 255)/256, 256, 0, stream>>>(Wp2, wh + 786432, Hn*Dn);
  k_cvt_g<<<(640*512 + 255)/256, 256, 0, stream>>>(Wi, wh + 851968, 0);
  k_cvt_g<<<(640*512 + 255)/256, 256, 0, stream>>>(Wf, wh + 851968, 1);
  k_cvt_g<<<(640*512 + 255)/256, 256, 0, stream>>>(Wo, wh + 851968, 2);
  k_cvt_g<<<(640*512 + 255)/256, 256, 0, stream>>>(Wc, wh + 851968, 3);

  k_main<<<NB, NT, 0, stream>>>(X, Mm, pos, wh,
                                bi, bff, bo, bc, b1, b2, bp1, bp2, acc);
  k_fin<<<1, 64, 0, stream>>>(acc, (float*)d_out);
}